// Round 11
// baseline (170.621 us; speedup 1.0000x reference)
//
#include <hip/hip_runtime.h>

using bf16x8 = __attribute__((ext_vector_type(8))) __bf16;
using f32x4  = __attribute__((ext_vector_type(4))) float;
using f32x16 = __attribute__((ext_vector_type(16))) float;

__device__ __forceinline__ unsigned short f2bf(float f) {
  unsigned u = __builtin_bit_cast(unsigned, f);
  u += 0x7fffu + ((u >> 16) & 1u);
  return (unsigned short)(u >> 16);
}

__device__ __forceinline__ unsigned cvt_pk_bf16(float lo, float hi) {
  unsigned r;
  asm("v_cvt_pk_bf16_f32 %0, %1, %2" : "=v"(r) : "v"(lo), "v"(hi));
  return r;
}

// v_permlane32_swap_b32: a = {a.lo-half, b.lo-half}, b = {a.hi-half, b.hi-half}.
__device__ __forceinline__ void permswap(unsigned &a, unsigned &b) {
  asm("v_permlane32_swap_b32 %0, %1" : "+v"(a), "+v"(b));
}

__device__ __forceinline__ void gload_lds16(const void* g, void* l) {
  __builtin_amdgcn_global_load_lds((const __attribute__((address_space(1))) void*)g,
                                   (__attribute__((address_space(3))) void*)l, 16, 0, 0);
}

// ---------------- fused prep: x fp32->bf16 + W_attn/W_proj transpose+convert ----------------
__global__ void prep_kernel(const float* __restrict__ x, unsigned short* __restrict__ xb,
                            const float* __restrict__ Wa, unsigned short* __restrict__ WaT,
                            const float* __restrict__ Wp, unsigned short* __restrict__ WpT) {
  __shared__ float tile[32][33];
  const int bid = blockIdx.x;
  const int tid = threadIdx.x;
  if (bid < 8192) {
    int i = (bid * 256 + tid) * 4;
    float4 f = *(const float4*)(x + i);
    ushort4 o;
    o.x = f2bf(f.x); o.y = f2bf(f.y); o.z = f2bf(f.z); o.w = f2bf(f.w);
    *(ushort4*)(xb + i) = o;
    return;
  }
  const float* W; unsigned short* WT; int N, tb;
  if (bid < 11264) { W = Wa; WT = WaT; N = 3072; tb = bid - 8192; }
  else             { W = Wp; WT = WpT; N = 1024; tb = bid - 11264; }
  const int nt = N >> 5;
  const int n0 = (tb % nt) * 32, k0 = (tb / nt) * 32;
  const int tx = tid & 31, ty = tid >> 5;
  #pragma unroll
  for (int i = 0; i < 32; i += 8)
    tile[ty + i][tx] = W[(size_t)(k0 + ty + i) * N + (n0 + tx)];
  __syncthreads();
  #pragma unroll
  for (int i = 0; i < 32; i += 8)
    WT[(size_t)(n0 + ty + i) * 1024 + (k0 + tx)] = f2bf(tile[tx][ty + i]);
}

// ---------------- bf16 GEMM: C[M][N] = A[M][K] * BT[N][K]^T (R9 proven 128^2) ----------------
// MODE 0: q (bn<8, pre-scaled by (1/8)*log2e) / k scatter bf16 head-major;
//         v-region (bn>=16) LDS-bounce -> vT[bh][d][t].
// MODE 1: fp32 store.
template <int MODE>
__global__ __launch_bounds__(256, 2)
void gemm_bf16(const unsigned short* __restrict__ A,
               const unsigned short* __restrict__ BT,
               float* __restrict__ Cout, int K,
               unsigned short* __restrict__ q_out,
               unsigned short* __restrict__ k_out,
               unsigned short* __restrict__ v_out, int N) {
  __shared__ alignas(16) char smem[32768];
  char* As = smem;
  char* Bs = smem + 16384;
  const int tid = threadIdx.x;
  const int lane = tid & 63, w = tid >> 6;
  const int wm = w >> 1, wn = w & 1;
  const int l15 = lane & 15, l4 = lane >> 4;
  const int bm = blockIdx.y, bn = blockIdx.x;

  f32x4 acc[4][4] = {};

  for (int kt = 0; kt < K; kt += 64) {
    #pragma unroll
    for (int i = 0; i < 4; i++) {
      int row = i * 32 + w * 8 + (lane >> 3);
      int sc = (lane & 7) ^ (row & 7);
      gload_lds16(A + (size_t)(bm * 128 + row) * K + kt + sc * 8, As + i * 4096 + w * 1024);
      gload_lds16(BT + (size_t)(bn * 128 + row) * K + kt + sc * 8, Bs + i * 4096 + w * 1024);
    }
    __syncthreads();
    #pragma unroll
    for (int kk = 0; kk < 2; kk++) {
      bf16x8 af[4], bfr[4];
      #pragma unroll
      for (int mc = 0; mc < 4; mc++) {
        int row = wm * 64 + mc * 16 + l15;
        af[mc] = *(const bf16x8*)(As + row * 128 + (((kk * 4 + l4) ^ (row & 7)) << 4));
      }
      #pragma unroll
      for (int nc = 0; nc < 4; nc++) {
        int row = wn * 64 + nc * 16 + l15;
        bfr[nc] = *(const bf16x8*)(Bs + row * 128 + (((kk * 4 + l4) ^ (row & 7)) << 4));
      }
      #pragma unroll
      for (int mc = 0; mc < 4; mc++)
        #pragma unroll
        for (int nc = 0; nc < 4; nc++)
          acc[mc][nc] = __builtin_amdgcn_mfma_f32_16x16x32_bf16(af[mc], bfr[nc], acc[mc][nc], 0, 0, 0);
    }
    __syncthreads();
  }

  if (MODE == 0 && bn >= 16) {
    // ---- V region: bounce through LDS, store transposed vT[bh][d][t] ----
    unsigned short* tt = (unsigned short*)smem;
    #pragma unroll
    for (int mc = 0; mc < 4; mc++)
      #pragma unroll
      for (int nc = 0; nc < 4; nc++)
        #pragma unroll
        for (int r = 0; r < 4; r++) {
          int ml = wm * 64 + mc * 16 + l4 * 4 + r;
          int nl = wn * 64 + nc * 16 + l15;
          tt[nl * 128 + (ml ^ ((nl & 7) << 3))] = f2bf(acc[mc][nc][r]);
        }
    __syncthreads();
    const int b_ = bm >> 4;
    const int t0 = (bm & 15) * 128;
    const int mm = (tid & 15) * 8;
    #pragma unroll
    for (int it = 0; it < 8; it++) {
      int nl = it * 16 + (tid >> 4);
      int n = bn * 128 + nl;
      int h = (n >> 6) & 15, d = n & 63;
      int4 val = *(const int4*)&tt[nl * 128 + (mm ^ ((nl & 7) << 3))];
      *(int4*)(v_out + ((size_t)(b_ * 16 + h) * 64 + d) * 2048 + t0 + mm) = val;
    }
  } else {
    const float qsc = (MODE == 0 && bn < 8) ? 0.18033688f : 1.0f;  // (1/8)*log2(e) folded into Q
    #pragma unroll
    for (int mc = 0; mc < 4; mc++) {
      #pragma unroll
      for (int nc = 0; nc < 4; nc++) {
        #pragma unroll
        for (int r = 0; r < 4; r++) {
          int m = bm * 128 + wm * 64 + mc * 16 + l4 * 4 + r;
          int n = bn * 128 + wn * 64 + nc * 16 + l15;
          float val = acc[mc][nc][r] * qsc;
          if (MODE == 0) {
            int b = m >> 11, t = m & 2047;
            int which = n >> 10, h = (n >> 6) & 15, d = n & 63;
            unsigned short* dst = (which == 0) ? q_out : k_out;
            dst[(((size_t)(b * 16 + h)) * 2048 + t) * 64 + d] = f2bf(val);
          } else {
            Cout[(size_t)m * N + n] = val;
          }
        }
      }
    }
  }
}

// Repack one 16-reg C-layout block (32 keys x q) into two PV A-frags.
__device__ __forceinline__ void repack_pa(const f32x16 s, bf16x8 &fl, bf16x8 &fh) {
  unsigned p01 = cvt_pk_bf16(s[0], s[1]);
  unsigned p23 = cvt_pk_bf16(s[2], s[3]);
  unsigned p45 = cvt_pk_bf16(s[4], s[5]);
  unsigned p67 = cvt_pk_bf16(s[6], s[7]);
  unsigned p89 = cvt_pk_bf16(s[8], s[9]);
  unsigned pAB = cvt_pk_bf16(s[10], s[11]);
  unsigned pCD = cvt_pk_bf16(s[12], s[13]);
  unsigned pEF = cvt_pk_bf16(s[14], s[15]);
  permswap(p01, p45);
  permswap(p23, p67);
  permswap(p89, pCD);
  permswap(pAB, pEF);
  uint4 f0, f1;
  f0.x = p01; f0.y = p23; f0.z = p45; f0.w = p67;
  f1.x = p89; f1.y = pAB; f1.z = pCD; f1.w = pEF;
  fl = __builtin_bit_cast(bf16x8, f0);
  fh = __builtin_bit_cast(bf16x8, f1);
}

// ---------------- flash attention: 2 waves x 64 q, K/V frags read once per wave ----------------
// 1024 blocks, 128 threads. qt = 15 - bid/64, bh = bid%64. Wave w owns q rows
// [qt*128 + w*64, +64) as two 32-row groups. Per tile: 8 ds_read for K frags
// (shared by both groups), 8 for V frags -> half the LDS traffic of the 4-wave
// 32q/wave layout. Staging: 8 gload_lds per thread, dbuf, vmcnt(8).
__global__ __launch_bounds__(128, 2)
void attn_kernel(const unsigned short* __restrict__ q,
                 const unsigned short* __restrict__ k,
                 const unsigned short* __restrict__ vT,
                 unsigned short* __restrict__ att) {
  __shared__ alignas(16) char smem[32768];   // K: [2][8192] @0, V^T: [2][8192] @16384

  const int bid = blockIdx.x;
  const int qt = 15 - (bid >> 6);
  const int bh = bid & 63;
  const int tid = threadIdx.x;               // 0..127
  const int lane = tid & 63, w = tid >> 6;   // 2 waves
  const int l31 = lane & 31, hi = lane >> 5;
  const size_t base = (size_t)bh * 2048 * 64;

  const int qwb = qt * 128 + w * 64;         // wave's first q row
  // Q fragments: 2 groups of 32 rows
  bf16x8 qf0[4], qf1[4];
  #pragma unroll
  for (int ks = 0; ks < 4; ks++) {
    qf0[ks] = *(const bf16x8*)(q + base + (size_t)(qwb + l31) * 64 + ks * 16 + hi * 8);
    qf1[ks] = *(const bf16x8*)(q + base + (size_t)(qwb + 32 + l31) * 64 + ks * 16 + hi * 8);
  }
  asm volatile("" :: "v"(qf0[0]), "v"(qf0[1]), "v"(qf0[2]), "v"(qf0[3]),
                     "v"(qf1[0]), "v"(qf1[1]), "v"(qf1[2]), "v"(qf1[3]));

  // fragment base pointers (K and V share swizzle): row l31, chunk (2ks+hi)^(l31&7)
  const char* kb4[4];
  #pragma unroll
  for (int ks = 0; ks < 4; ks++)
    kb4[ks] = smem + l31 * 128 + (((2 * ks + hi) ^ (l31 & 7)) << 4);

  // staging geometry: load j covers rows j*16 + w*8 + (lane>>3); (j*16)&7==0 so
  // the swizzled chunk is j-independent.
  const int srow8 = w * 8 + (lane >> 3);             // 0..15
  const int sc8 = ((lane & 7) ^ (srow8 & 7)) * 8;    // elems

  f32x16 o00 = {}, o01 = {}, o10 = {}, o11 = {}, lacc0 = {}, lacc1 = {};
  const int qmax = qwb + 63;
  const int ntiles = 2 * qt + 2;                     // even

  uint4 onesw;
  onesw.x = 0x3F803F80u; onesw.y = 0x3F803F80u; onesw.z = 0x3F803F80u; onesw.w = 0x3F803F80u;
  const bf16x8 onesv = __builtin_bit_cast(bf16x8, onesw);

  // prologue: stage tile 0 -> buf0 (8 loads/thread)
  {
    const unsigned short* kp = k + base + (size_t)srow8 * 64 + sc8;
    const unsigned short* vp = vT + base + (size_t)srow8 * 2048 + sc8;
    #pragma unroll
    for (int j = 0; j < 4; j++) {
      gload_lds16(kp + j * 1024,  smem + j * 2048 + w * 1024);
      gload_lds16(vp + j * 32768, smem + 16384 + j * 2048 + w * 1024);
    }
  }
  const unsigned short* kq1 = k + base + (size_t)srow8 * 64 + sc8 + 4096;
  const unsigned short* kq2 = kq1 + 4096;
  const unsigned short* vq1 = vT + base + (size_t)srow8 * 2048 + sc8 + 64;
  const unsigned short* vq2 = vq1 + 64;

#define STAGE(BUF, KP, VP)                                                     \
  do {                                                                         \
    _Pragma("unroll")                                                          \
    for (int j = 0; j < 4; j++) {                                              \
      gload_lds16((KP) + j * 1024,  smem + (BUF) + j * 2048 + w * 1024);       \
      gload_lds16((VP) + j * 32768, smem + 16384 + (BUF) + j * 2048 + w * 1024);\
    }                                                                          \
  } while (0)

#define COMPUTE_TILE(BUF, KBASE)                                               \
  do {                                                                         \
    const int kbase_ = (KBASE);                                                \
    if (kbase_ <= qmax) {                                                      \
      /* K frags once, shared by both q-groups */                              \
      bf16x8 kf[4][2];                                                         \
      _Pragma("unroll")                                                        \
      for (int ks = 0; ks < 4; ks++) {                                         \
        kf[ks][0] = *(const bf16x8*)(kb4[ks] + (BUF));                         \
        kf[ks][1] = *(const bf16x8*)(kb4[ks] + (BUF) + 4096);                  \
      }                                                                        \
      bf16x8 pa0[4], pa1[4];                                                   \
      /* ---- group 0 ---- */                                                  \
      {                                                                        \
        f32x16 s0 = {}, s1 = {};                                               \
        __builtin_amdgcn_s_setprio(1);                                         \
        _Pragma("unroll")                                                      \
        for (int ks = 0; ks < 4; ks++) {                                       \
          s0 = __builtin_amdgcn_mfma_f32_32x32x16_bf16(kf[ks][0], qf0[ks], s0, 0, 0, 0); \
          s1 = __builtin_amdgcn_mfma_f32_32x32x16_bf16(kf[ks][1], qf0[ks], s1, 0, 0, 0); \
        }                                                                      \
        __builtin_amdgcn_s_setprio(0);                                         \
        const int qrow_ = qwb + l31;                                           \
        if (kbase_ + 63 > qwb) {                                               \
          _Pragma("unroll")                                                    \
          for (int r = 0; r < 16; r++) {                                       \
            int crow = (r & 3) + 8 * (r >> 2) + 4 * hi;                        \
            if (kbase_ + crow > qrow_) s0[r] = -1e30f;                         \
            if (kbase_ + 32 + crow > qrow_) s1[r] = -1e30f;                    \
          }                                                                    \
        }                                                                      \
        _Pragma("unroll")                                                      \
        for (int r = 0; r < 16; r++) {                                         \
          float t0_ = s0[r], t1_ = s1[r];                                      \
          asm("v_exp_f32 %0, %0" : "+v"(t0_));                                 \
          asm("v_exp_f32 %0, %0" : "+v"(t1_));                                 \
          s0[r] = t0_; s1[r] = t1_;                                            \
        }                                                                      \
        repack_pa(s0, pa0[0], pa0[1]);                                         \
        repack_pa(s1, pa0[2], pa0[3]);                                         \
      }                                                                        \
      /* ---- group 1 ---- */                                                  \
      {                                                                        \
        f32x16 s0 = {}, s1 = {};                                               \
        __builtin_amdgcn_s_setprio(1);                                         \
        _Pragma("unroll")                                                      \
        for (int ks = 0; ks < 4; ks++) {                                       \
          s0 = __builtin_amdgcn_mfma_f32_32x32x16_bf16(kf[ks][0], qf1[ks], s0, 0, 0, 0); \
          s1 = __builtin_amdgcn_mfma_f32_32x32x16_bf16(kf[ks][1], qf1[ks], s1, 0, 0, 0); \
        }                                                                      \
        __builtin_amdgcn_s_setprio(0);                                         \
        const int qrow_ = qwb + 32 + l31;                                      \
        if (kbase_ + 63 > qwb + 32) {                                          \
          _Pragma("unroll")                                                    \
          for (int r = 0; r < 16; r++) {                                       \
            int crow = (r & 3) + 8 * (r >> 2) + 4 * hi;                        \
            if (kbase_ + crow > qrow_) s0[r] = -1e30f;                         \
            if (kbase_ + 32 + crow > qrow_) s1[r] = -1e30f;                    \
          }                                                                    \
        }                                                                      \
        _Pragma("unroll")                                                      \
        for (int r = 0; r < 16; r++) {                                         \
          float t0_ = s0[r], t1_ = s1[r];                                      \
          asm("v_exp_f32 %0, %0" : "+v"(t0_));                                 \
          asm("v_exp_f32 %0, %0" : "+v"(t1_));                                 \
          s0[r] = t0_; s1[r] = t1_;                                            \
        }                                                                      \
        repack_pa(s0, pa1[0], pa1[1]);                                         \
        repack_pa(s1, pa1[2], pa1[3]);                                         \
      }                                                                        \
      /* ---- PV both groups; V frags read once ---- */                        \
      __builtin_amdgcn_s_setprio(1);                                           \
      _Pragma("unroll")                                                        \
      for (int ks = 0; ks < 4; ks++) {                                         \
        bf16x8 vf0 = *(const bf16x8*)(kb4[ks] + 16384 + (BUF));                \
        bf16x8 vf1 = *(const bf16x8*)(kb4[ks] + 16384 + (BUF) + 4096);         \
        o00 = __builtin_amdgcn_mfma_f32_32x32x16_bf16(pa0[ks], vf0, o00, 0, 0, 0); \
        o01 = __builtin_amdgcn_mfma_f32_32x32x16_bf16(pa0[ks], vf1, o01, 0, 0, 0); \
        o10 = __builtin_amdgcn_mfma_f32_32x32x16_bf16(pa1[ks], vf0, o10, 0, 0, 0); \
        o11 = __builtin_amdgcn_mfma_f32_32x32x16_bf16(pa1[ks], vf1, o11, 0, 0, 0); \
        lacc0 = __builtin_amdgcn_mfma_f32_32x32x16_bf16(pa0[ks], onesv, lacc0, 0, 0, 0); \
        lacc1 = __builtin_amdgcn_mfma_f32_32x32x16_bf16(pa1[ks], onesv, lacc1, 0, 0, 0); \
      }                                                                        \
      __builtin_amdgcn_s_setprio(0);                                           \
    }                                                                          \
  } while (0)

  for (int t = 0; t < ntiles; t += 2) {
    // ---- even tile t (buf0); stage tile t+1 -> buf1 (always exists) ----
    STAGE(8192, kq1, vq1);
    kq1 += 8192; vq1 += 128;
    asm volatile("s_waitcnt vmcnt(8)" ::: "memory");
    __builtin_amdgcn_s_barrier();
    __builtin_amdgcn_sched_barrier(0);
    COMPUTE_TILE(0, t * 64);
    __builtin_amdgcn_s_barrier();
    __builtin_amdgcn_sched_barrier(0);

    // ---- odd tile t+1 (buf1); stage tile t+2 -> buf0 (if exists) ----
    if (t + 2 < ntiles) {
      STAGE(0, kq2, vq2);
      kq2 += 8192; vq2 += 128;
      asm volatile("s_waitcnt vmcnt(8)" ::: "memory");
    } else {
      asm volatile("s_waitcnt vmcnt(0)" ::: "memory");
    }
    __builtin_amdgcn_s_barrier();
    __builtin_amdgcn_sched_barrier(0);
    COMPUTE_TILE(8192, t * 64 + 64);
    __builtin_amdgcn_s_barrier();
    __builtin_amdgcn_sched_barrier(0);
  }
#undef COMPUTE_TILE
#undef STAGE

  // ---- epilogue: two groups ----
  const int b_ = bh >> 4, h = bh & 15;
  #pragma unroll
  for (int r = 0; r < 16; r++) {
    int crow = (r & 3) + 8 * (r >> 2) + 4 * hi;
    {
      float li = 1.0f / lacc0[r];
      int t = qwb + crow;
      size_t rb = ((size_t)(b_ * 2048 + t)) * 1024 + h * 64;
      att[rb + l31] = f2bf(o00[r] * li);
      att[rb + 32 + l31] = f2bf(o01[r] * li);
    }
    {
      float li = 1.0f / lacc1[r];
      int t = qwb + 32 + crow;
      size_t rb = ((size_t)(b_ * 2048 + t)) * 1024 + h * 64;
      att[rb + l31] = f2bf(o10[r] * li);
      att[rb + 32 + l31] = f2bf(o11[r] * li);
    }
  }
}

// ---------------- launch ----------------
extern "C" void kernel_launch(void* const* d_in, const int* in_sizes, int n_in,
                              void* d_out, int out_size, void* d_ws, size_t ws_size,
                              hipStream_t stream) {
  const float* x  = (const float*)d_in[0];   // [4,2048,1024]
  const float* Wa = (const float*)d_in[1];   // [1024,3072]
  const float* Wp = (const float*)d_in[2];   // [1024,1024]
  float* out = (float*)d_out;                // [4,2048,1024] fp32
  char* ws = (char*)d_ws;

  unsigned short* xb  = (unsigned short*)(ws);                 // 16 MB
  unsigned short* WaT = (unsigned short*)(ws + 16777216);      // 6 MB
  unsigned short* WpT = (unsigned short*)(ws + 23068672);      // 2 MB
  unsigned short* qb  = (unsigned short*)(ws + 25165824);      // 16 MB
  unsigned short* kb  = (unsigned short*)(ws + 41943040);      // 16 MB
  unsigned short* vtb = (unsigned short*)(ws + 58720256);      // 16 MB (vT[bh][d][t])
  unsigned short* att = xb;                                    // reuse xb after GEMM1

  prep_kernel<<<12288, 256, 0, stream>>>(x, xb, Wa, WaT, Wp, WpT);

  gemm_bf16<0><<<dim3(24, 64), 256, 0, stream>>>(xb, WaT, nullptr, 1024, qb, kb, vtb, 3072);

  attn_kernel<<<1024, 128, 0, stream>>>(qb, kb, vtb, att);

  gemm_bf16<1><<<dim3(8, 64), 256, 0, stream>>>(att, WpT, out, 1024, nullptr, nullptr, nullptr, 1024);
}

// Round 12
// 144.404 us; speedup vs baseline: 1.1816x; 1.1816x over previous
//
#include <hip/hip_runtime.h>

using bf16x8 = __attribute__((ext_vector_type(8))) __bf16;
using f32x4  = __attribute__((ext_vector_type(4))) float;
using f32x16 = __attribute__((ext_vector_type(16))) float;

__device__ __forceinline__ unsigned short f2bf(float f) {
  unsigned u = __builtin_bit_cast(unsigned, f);
  u += 0x7fffu + ((u >> 16) & 1u);
  return (unsigned short)(u >> 16);
}

__device__ __forceinline__ unsigned cvt_pk_bf16(float lo, float hi) {
  unsigned r;
  asm("v_cvt_pk_bf16_f32 %0, %1, %2" : "=v"(r) : "v"(lo), "v"(hi));
  return r;
}

// v_permlane32_swap_b32: a = {a.lo-half, b.lo-half}, b = {a.hi-half, b.hi-half}.
__device__ __forceinline__ void permswap(unsigned &a, unsigned &b) {
  asm("v_permlane32_swap_b32 %0, %1" : "+v"(a), "+v"(b));
}

__device__ __forceinline__ void gload_lds16(const void* g, void* l) {
  __builtin_amdgcn_global_load_lds((const __attribute__((address_space(1))) void*)g,
                                   (__attribute__((address_space(3))) void*)l, 16, 0, 0);
}

// ---------------- fused prep: x fp32->bf16 + W_attn/W_proj transpose+convert ----------------
__global__ void prep_kernel(const float* __restrict__ x, unsigned short* __restrict__ xb,
                            const float* __restrict__ Wa, unsigned short* __restrict__ WaT,
                            const float* __restrict__ Wp, unsigned short* __restrict__ WpT) {
  __shared__ float tile[32][33];
  const int bid = blockIdx.x;
  const int tid = threadIdx.x;
  if (bid < 8192) {
    int i = (bid * 256 + tid) * 4;
    float4 f = *(const float4*)(x + i);
    ushort4 o;
    o.x = f2bf(f.x); o.y = f2bf(f.y); o.z = f2bf(f.z); o.w = f2bf(f.w);
    *(ushort4*)(xb + i) = o;
    return;
  }
  const float* W; unsigned short* WT; int N, tb;
  if (bid < 11264) { W = Wa; WT = WaT; N = 3072; tb = bid - 8192; }
  else             { W = Wp; WT = WpT; N = 1024; tb = bid - 11264; }
  const int nt = N >> 5;
  const int n0 = (tb % nt) * 32, k0 = (tb / nt) * 32;
  const int tx = tid & 31, ty = tid >> 5;
  #pragma unroll
  for (int i = 0; i < 32; i += 8)
    tile[ty + i][tx] = W[(size_t)(k0 + ty + i) * N + (n0 + tx)];
  __syncthreads();
  #pragma unroll
  for (int i = 0; i < 32; i += 8)
    WT[(size_t)(n0 + ty + i) * 1024 + (k0 + tx)] = f2bf(tile[tx][ty + i]);
}

// ---------------- bf16 GEMM: C[M][N] = A[M][K] * BT[N][K]^T (R9 proven 128^2) ----------------
// 1D grid, XCD-patch swizzle (assumes xcd = bid % 8 round-robin; wrong guess = perf-only).
// MODE 0 (1536 blocks): each XCD owns a 6-bn x 32-bm patch. q (bn<8, pre-scaled) / k
//         scatter head-major; v-region (bn>=16) LDS-bounce -> vT[bh][d][t].
// MODE 1 (512 blocks): each XCD owns 8 bm-rows x all 8 bn (A-chunk 2MB + B 2MB in L2).
template <int MODE>
__global__ __launch_bounds__(256, 2)
void gemm_bf16(const unsigned short* __restrict__ A,
               const unsigned short* __restrict__ BT,
               float* __restrict__ Cout, int K,
               unsigned short* __restrict__ q_out,
               unsigned short* __restrict__ k_out,
               unsigned short* __restrict__ v_out, int N) {
  __shared__ alignas(16) char smem[32768];
  char* As = smem;
  char* Bs = smem + 16384;
  const int tid = threadIdx.x;
  const int lane = tid & 63, w = tid >> 6;
  const int wm = w >> 1, wn = w & 1;
  const int l15 = lane & 15, l4 = lane >> 4;

  // XCD-patch block decode
  const int bid = blockIdx.x;
  const int xcd = bid & 7, off = bid >> 3;
  int bm, bn;
  if (MODE == 0) {
    bn = (xcd & 3) * 6 + off % 6;           // 0..23
    bm = (xcd >> 2) * 32 + off / 6;         // 0..63
  } else {
    bn = off & 7;                           // 0..7
    bm = xcd * 8 + (off >> 3);              // 0..63
  }

  f32x4 acc[4][4] = {};

  for (int kt = 0; kt < K; kt += 64) {
    #pragma unroll
    for (int i = 0; i < 4; i++) {
      int row = i * 32 + w * 8 + (lane >> 3);
      int sc = (lane & 7) ^ (row & 7);
      gload_lds16(A + (size_t)(bm * 128 + row) * K + kt + sc * 8, As + i * 4096 + w * 1024);
      gload_lds16(BT + (size_t)(bn * 128 + row) * K + kt + sc * 8, Bs + i * 4096 + w * 1024);
    }
    __syncthreads();
    #pragma unroll
    for (int kk = 0; kk < 2; kk++) {
      bf16x8 af[4], bfr[4];
      #pragma unroll
      for (int mc = 0; mc < 4; mc++) {
        int row = wm * 64 + mc * 16 + l15;
        af[mc] = *(const bf16x8*)(As + row * 128 + (((kk * 4 + l4) ^ (row & 7)) << 4));
      }
      #pragma unroll
      for (int nc = 0; nc < 4; nc++) {
        int row = wn * 64 + nc * 16 + l15;
        bfr[nc] = *(const bf16x8*)(Bs + row * 128 + (((kk * 4 + l4) ^ (row & 7)) << 4));
      }
      #pragma unroll
      for (int mc = 0; mc < 4; mc++)
        #pragma unroll
        for (int nc = 0; nc < 4; nc++)
          acc[mc][nc] = __builtin_amdgcn_mfma_f32_16x16x32_bf16(af[mc], bfr[nc], acc[mc][nc], 0, 0, 0);
    }
    __syncthreads();
  }

  if (MODE == 0 && bn >= 16) {
    // ---- V region: bounce through LDS, store transposed vT[bh][d][t] ----
    unsigned short* tt = (unsigned short*)smem;
    #pragma unroll
    for (int mc = 0; mc < 4; mc++)
      #pragma unroll
      for (int nc = 0; nc < 4; nc++)
        #pragma unroll
        for (int r = 0; r < 4; r++) {
          int ml = wm * 64 + mc * 16 + l4 * 4 + r;
          int nl = wn * 64 + nc * 16 + l15;
          tt[nl * 128 + (ml ^ ((nl & 7) << 3))] = f2bf(acc[mc][nc][r]);
        }
    __syncthreads();
    const int b_ = bm >> 4;
    const int t0 = (bm & 15) * 128;
    const int mm = (tid & 15) * 8;
    #pragma unroll
    for (int it = 0; it < 8; it++) {
      int nl = it * 16 + (tid >> 4);
      int n = bn * 128 + nl;
      int h = (n >> 6) & 15, d = n & 63;
      int4 val = *(const int4*)&tt[nl * 128 + (mm ^ ((nl & 7) << 3))];
      *(int4*)(v_out + ((size_t)(b_ * 16 + h) * 64 + d) * 2048 + t0 + mm) = val;
    }
  } else {
    const float qsc = (MODE == 0 && bn < 8) ? 0.18033688f : 1.0f;  // (1/8)*log2(e) folded into Q
    #pragma unroll
    for (int mc = 0; mc < 4; mc++) {
      #pragma unroll
      for (int nc = 0; nc < 4; nc++) {
        #pragma unroll
        for (int r = 0; r < 4; r++) {
          int m = bm * 128 + wm * 64 + mc * 16 + l4 * 4 + r;
          int n = bn * 128 + wn * 64 + nc * 16 + l15;
          float val = acc[mc][nc][r] * qsc;
          if (MODE == 0) {
            int b = m >> 11, t = m & 2047;
            int which = n >> 10, h = (n >> 6) & 15, d = n & 63;
            unsigned short* dst = (which == 0) ? q_out : k_out;
            dst[(((size_t)(b * 16 + h)) * 2048 + t) * 64 + d] = f2bf(val);
          } else {
            Cout[(size_t)m * N + n] = val;
          }
        }
      }
    }
  }
}

// Repack one 16-reg C-layout block (32 keys x q) into two PV A-frags.
__device__ __forceinline__ void repack_pa(const f32x16 s, bf16x8 &fl, bf16x8 &fh) {
  unsigned p01 = cvt_pk_bf16(s[0], s[1]);
  unsigned p23 = cvt_pk_bf16(s[2], s[3]);
  unsigned p45 = cvt_pk_bf16(s[4], s[5]);
  unsigned p67 = cvt_pk_bf16(s[6], s[7]);
  unsigned p89 = cvt_pk_bf16(s[8], s[9]);
  unsigned pAB = cvt_pk_bf16(s[10], s[11]);
  unsigned pCD = cvt_pk_bf16(s[12], s[13]);
  unsigned pEF = cvt_pk_bf16(s[14], s[15]);
  permswap(p01, p45);
  permswap(p23, p67);
  permswap(p89, pCD);
  permswap(pAB, pEF);
  uint4 f0, f1;
  f0.x = p01; f0.y = p23; f0.z = p45; f0.w = p67;
  f1.x = p89; f1.y = pAB; f1.z = pCD; f1.w = pEF;
  fl = __builtin_bit_cast(bf16x8, f0);
  fh = __builtin_bit_cast(bf16x8, f1);
}

// ---------------- flash attention (R7 proven, unchanged) ----------------
__global__ __launch_bounds__(256, 4)
void attn_kernel(const unsigned short* __restrict__ q,
                 const unsigned short* __restrict__ k,
                 const unsigned short* __restrict__ vT,
                 unsigned short* __restrict__ att) {
  __shared__ alignas(16) char smem[32768];   // K: [2][8192] @0, V^T: [2][8192] @16384

  const int bid = blockIdx.x;
  const int qt = 15 - (bid >> 6);
  const int bh = bid & 63;
  const int tid = threadIdx.x;
  const int lane = tid & 63, w = tid >> 6;
  const int l31 = lane & 31, hi = lane >> 5;
  const size_t base = (size_t)bh * 2048 * 64;

  bf16x8 qf[4];
  const int qwb = qt * 128 + w * 32;
  const int qrow = qwb + l31;
  #pragma unroll
  for (int ks = 0; ks < 4; ks++)
    qf[ks] = *(const bf16x8*)(q + base + (size_t)qrow * 64 + ks * 16 + hi * 8);
  asm volatile("" :: "v"(qf[0]), "v"(qf[1]), "v"(qf[2]), "v"(qf[3]));

  const char* kb4[4];
  #pragma unroll
  for (int ks = 0; ks < 4; ks++)
    kb4[ks] = smem + l31 * 128 + (((2 * ks + hi) ^ (l31 & 7)) << 4);

  const int srow = w * 8 + (lane >> 3);
  const int sc8 = ((lane & 7) ^ (srow & 7)) * 8;

  f32x16 o0 = {}, o1 = {}, lacc = {};
  const int qmax = qwb + 31;
  const int ntiles = 2 * qt + 2;

  uint4 onesw;
  onesw.x = 0x3F803F80u; onesw.y = 0x3F803F80u; onesw.z = 0x3F803F80u; onesw.w = 0x3F803F80u;
  const bf16x8 onesv = __builtin_bit_cast(bf16x8, onesw);

  {
    const unsigned short* kp = k + base + srow * 64 + sc8;
    gload_lds16(kp,         smem + w * 1024);
    gload_lds16(kp + 2048,  smem + 4096 + w * 1024);
    const unsigned short* vp = vT + base + (size_t)srow * 2048 + sc8;
    gload_lds16(vp,          smem + 16384 + w * 1024);
    gload_lds16(vp + 65536,  smem + 16384 + 4096 + w * 1024);
  }
  const unsigned short* kq1 = k + base + srow * 64 + sc8 + 4096;
  const unsigned short* kq2 = kq1 + 4096;
  const unsigned short* vq1 = vT + base + (size_t)srow * 2048 + sc8 + 64;
  const unsigned short* vq2 = vq1 + 64;

#define COMPUTE_TILE(BUF, KBASE)                                               \
  do {                                                                         \
    const int kbase_ = (KBASE);                                                \
    if (kbase_ <= qmax) {                                                      \
      f32x16 s0 = {}, s1 = {};                                                 \
      __builtin_amdgcn_s_setprio(1);                                           \
      _Pragma("unroll")                                                        \
      for (int ks = 0; ks < 4; ks++) {                                         \
        bf16x8 k0 = *(const bf16x8*)(kb4[ks] + (BUF));                         \
        bf16x8 k1 = *(const bf16x8*)(kb4[ks] + (BUF) + 4096);                  \
        s0 = __builtin_amdgcn_mfma_f32_32x32x16_bf16(k0, qf[ks], s0, 0, 0, 0); \
        s1 = __builtin_amdgcn_mfma_f32_32x32x16_bf16(k1, qf[ks], s1, 0, 0, 0); \
      }                                                                        \
      __builtin_amdgcn_s_setprio(0);                                           \
      if (kbase_ + 63 > qwb) {                                                 \
        _Pragma("unroll")                                                      \
        for (int r = 0; r < 16; r++) {                                         \
          int crow = (r & 3) + 8 * (r >> 2) + 4 * hi;                          \
          if (kbase_ + crow > qrow) s0[r] = -1e30f;                            \
          if (kbase_ + 32 + crow > qrow) s1[r] = -1e30f;                       \
        }                                                                      \
      }                                                                        \
      _Pragma("unroll")                                                        \
      for (int r = 0; r < 16; r++) {                                           \
        float t0_ = s0[r], t1_ = s1[r];                                        \
        asm("v_exp_f32 %0, %0" : "+v"(t0_));                                   \
        asm("v_exp_f32 %0, %0" : "+v"(t1_));                                   \
        s0[r] = t0_; s1[r] = t1_;                                              \
      }                                                                        \
      bf16x8 pa[4];                                                            \
      repack_pa(s0, pa[0], pa[1]);                                             \
      repack_pa(s1, pa[2], pa[3]);                                             \
      __builtin_amdgcn_s_setprio(1);                                           \
      _Pragma("unroll")                                                        \
      for (int ks = 0; ks < 4; ks++) {                                         \
        bf16x8 vf0 = *(const bf16x8*)(kb4[ks] + 16384 + (BUF));                \
        bf16x8 vf1 = *(const bf16x8*)(kb4[ks] + 16384 + (BUF) + 4096);         \
        o0 = __builtin_amdgcn_mfma_f32_32x32x16_bf16(pa[ks], vf0, o0, 0, 0, 0);\
        o1 = __builtin_amdgcn_mfma_f32_32x32x16_bf16(pa[ks], vf1, o1, 0, 0, 0);\
        lacc = __builtin_amdgcn_mfma_f32_32x32x16_bf16(pa[ks], onesv, lacc, 0, 0, 0);\
      }                                                                        \
      __builtin_amdgcn_s_setprio(0);                                           \
    }                                                                          \
  } while (0)

  for (int t = 0; t < ntiles; t += 2) {
    gload_lds16(kq1,         smem + 8192 + w * 1024);
    gload_lds16(kq1 + 2048,  smem + 8192 + 4096 + w * 1024);
    gload_lds16(vq1,         smem + 16384 + 8192 + w * 1024);
    gload_lds16(vq1 + 65536, smem + 16384 + 8192 + 4096 + w * 1024);
    kq1 += 8192; vq1 += 128;
    asm volatile("s_waitcnt vmcnt(4)" ::: "memory");
    __builtin_amdgcn_s_barrier();
    __builtin_amdgcn_sched_barrier(0);
    COMPUTE_TILE(0, t * 64);
    __builtin_amdgcn_s_barrier();
    __builtin_amdgcn_sched_barrier(0);

    if (t + 2 < ntiles) {
      gload_lds16(kq2,         smem + w * 1024);
      gload_lds16(kq2 + 2048,  smem + 4096 + w * 1024);
      gload_lds16(vq2,         smem + 16384 + w * 1024);
      gload_lds16(vq2 + 65536, smem + 16384 + 4096 + w * 1024);
      kq2 += 8192; vq2 += 128;
      asm volatile("s_waitcnt vmcnt(4)" ::: "memory");
    } else {
      asm volatile("s_waitcnt vmcnt(0)" ::: "memory");
    }
    __builtin_amdgcn_s_barrier();
    __builtin_amdgcn_sched_barrier(0);
    COMPUTE_TILE(8192, t * 64 + 64);
    __builtin_amdgcn_s_barrier();
    __builtin_amdgcn_sched_barrier(0);
  }
#undef COMPUTE_TILE

  const int b_ = bh >> 4, h = bh & 15;
  #pragma unroll
  for (int r = 0; r < 16; r++) {
    int crow = (r & 3) + 8 * (r >> 2) + 4 * hi;
    float li = 1.0f / lacc[r];
    int t = qt * 128 + w * 32 + crow;
    size_t rb = ((size_t)(b_ * 2048 + t)) * 1024 + h * 64;
    att[rb + l31] = f2bf(o0[r] * li);
    att[rb + 32 + l31] = f2bf(o1[r] * li);
  }
}

// ---------------- launch ----------------
extern "C" void kernel_launch(void* const* d_in, const int* in_sizes, int n_in,
                              void* d_out, int out_size, void* d_ws, size_t ws_size,
                              hipStream_t stream) {
  const float* x  = (const float*)d_in[0];   // [4,2048,1024]
  const float* Wa = (const float*)d_in[1];   // [1024,3072]
  const float* Wp = (const float*)d_in[2];   // [1024,1024]
  float* out = (float*)d_out;                // [4,2048,1024] fp32
  char* ws = (char*)d_ws;

  unsigned short* xb  = (unsigned short*)(ws);                 // 16 MB
  unsigned short* WaT = (unsigned short*)(ws + 16777216);      // 6 MB
  unsigned short* WpT = (unsigned short*)(ws + 23068672);      // 2 MB
  unsigned short* qb  = (unsigned short*)(ws + 25165824);      // 16 MB
  unsigned short* kb  = (unsigned short*)(ws + 41943040);      // 16 MB
  unsigned short* vtb = (unsigned short*)(ws + 58720256);      // 16 MB (vT[bh][d][t])
  unsigned short* att = xb;                                    // reuse xb after GEMM1

  prep_kernel<<<12288, 256, 0, stream>>>(x, xb, Wa, WaT, Wp, WpT);

  gemm_bf16<0><<<1536, 256, 0, stream>>>(xb, WaT, nullptr, 1024, qb, kb, vtb, 3072);

  attn_kernel<<<1024, 256, 0, stream>>>(qb, kb, vtb, att);

  gemm_bf16<1><<<512, 256, 0, stream>>>(att, WpT, out, 1024, nullptr, nullptr, nullptr, 1024);
}